// Round 1
// baseline (9.725 us; speedup 1.0000x reference)
//
#include <hip/hip_runtime.h>

// RRoI align. Output shape (32, 32, 32) f32.
// features: (1, 256(W), 256(H), 256(C)) f32 -> only features[0,0,:,:] used
//   (first 65536 floats, a 256x256 plane; row0[a,b] = feat[a*256+b]).
// rois: (1, 32, 6) f32. roi_idx = [0,0,1,...,30].
// ph = pw = 32, spatial_scale = 1 (fixed by setup_inputs).

__device__ __forceinline__ int fix_idx(int v) {
    // JAX/numpy gather semantics: negative wraps, OOB-positive clamps.
    if (v < 0) v += 256;
    if (v < 0) v = 0;
    if (v > 255) v = 255;
    return v;
}

__global__ __launch_bounds__(256) void rroi_align_kernel(
    const float* __restrict__ feat,   // features base; plane = first 65536 floats
    const float* __restrict__ rois,   // 32 x 6
    float* __restrict__ out)          // 32*32*32
{
#pragma clang fp contract(off)
    const int gid = blockIdx.x * 256 + threadIdx.x;
    if (gid >= 32 * 32 * 32) return;
    const int n = gid >> 10;          // output roi slot
    const int i = (gid >> 5) & 31;    // y index
    const int j = gid & 31;           // x index
    const int src = (n == 0) ? 0 : (n - 1);

    const float* r = rois + src * 6;
    const float M1 = r[1];
    const float M2 = r[2];
    const float M3 = r[3];
    const float M4 = r[4];
    // M5 = (r5 * 180.0) * PI, all f32 ops (PI literal rounds to same f32 as jnp)
    const float m5 = (r[5] * 180.0f) * 3.1415926535f;
    // trig in double, rounded to f32: correctly-rounded single-precision result
    const float Alpha = (float)cos((double)m5);
    const float Beta  = (float)sin((double)m5);

    const float roi_pw = (M4 / M3) * 32.0f;
    const float dx = -(roi_pw / 2.0f);
    const float dy = -16.0f;
    const float Sx = (M4 / roi_pw) * 1.0f;   // * spatial_scale(=1)
    const float Sy = M3 / 32.0f;             // / (ph * ss)
    const float Dx = M1 * 1.0f;
    const float Dy = M2 * 1.0f;

    const float M00 = Alpha * Sx;
    const float M01 = Beta * Sy;
    const float M02 = (M00 * dx + M01 * dy) + Dx;
    const float M10 = (-Beta) * Sx;
    const float M11 = Alpha * Sy;
    const float M12 = (M10 * dx + M11 * dy) + Dy;

    const float x  = (float)j;
    const float y  = (float)i;
    const float x1 = x + 1.0f;
    const float y1 = y + 1.0f;

    const float P0 = (M00 * x  + M01 * y ) + M02;
    const float P1 = (M10 * x  + M11 * y ) + M12;
    const float P2 = (M00 * x  + M01 * y1) + M02;
    const float P3 = (M10 * x  + M11 * y1) + M12;
    const float P4 = (M00 * x1 + M01 * y ) + M02;
    const float P5 = (M10 * x1 + M11 * y ) + M12;
    const float P6 = (M00 * x1 + M01 * y1) + M02;
    const float P7 = (M10 * x1 + M11 * y1) + M12;

    // jnp.round = round-half-to-even = rintf (RN mode)
    const float leftMost   = fmaxf(rintf(fminf(fminf(P0, P2), fminf(P4, P6))), 0.0f);
    const float rightMost  = fminf(rintf(fmaxf(fmaxf(P0, P2), fmaxf(P4, P6))), 255.0f);
    const float topMost    = fmaxf(rintf(fminf(fminf(P1, P3), fminf(P5, P7))), 0.0f);
    const float bottomMost = fminf(rintf(fmaxf(fmaxf(P1, P3), fmaxf(P5, P7))), 255.0f);

    const float bin_cx = (leftMost + rightMost) / 2.0f;
    const float bin_cy = (topMost + bottomMost) / 2.0f;

    const float flx = floorf(bin_cx);
    const float fly = floorf(bin_cy);
    const int il = (int)flx;
    const int ir = (int)ceilf(bin_cx);
    const int it = (int)fly;
    const int ib = (int)ceilf(bin_cy);
    const float rx = bin_cx - flx;   // exactly 0.0 or 0.5
    const float ry = bin_cy - fly;

    const int ail = fix_idx(il), air = fix_idx(ir);
    const int ait = fix_idx(it), aib = fix_idx(ib);

    // gv: truncate feature value toward zero (astype int32 -> float32)
    const float lt = (float)(int)feat[ail * 256 + ait];
    const float rt = (float)(int)feat[air * 256 + ait];
    const float lb = (float)(int)feat[ail * 256 + aib];
    const float rb = (float)(int)feat[air * 256 + aib];

    const float wlt = (1.0f - rx) * (1.0f - ry);
    const float wrt = rx * (1.0f - ry);
    const float wrb = rx * ry;
    const float wlb = (1.0f - rx) * ry;

    out[gid] = ((lt * wlt + rt * wrt) + rb * wrb) + lb * wlb;
}

extern "C" void kernel_launch(void* const* d_in, const int* in_sizes, int n_in,
                              void* d_out, int out_size, void* d_ws, size_t ws_size,
                              hipStream_t stream) {
    // d_in order per setup_inputs: pooled_height, pooled_width, spatial_scale,
    // features, rois. ph=pw=32, ss=1 are fixed scalars; hard-coded above.
    const float* feat = (const float*)d_in[3];
    const float* rois = (const float*)d_in[4];
    float* out = (float*)d_out;
    const int total = 32 * 32 * 32;
    rroi_align_kernel<<<(total + 255) / 256, 256, 0, stream>>>(feat, rois, out);
}